// Round 3
// baseline (4633.758 us; speedup 1.0000x reference)
//
#include <hip/hip_runtime.h>
#include <math.h>

#define Bq 64
#define Tq 512
#define Hq 1024
#define G4 4096
#define NBLK 256
#define NTHR 512

typedef __attribute__((ext_vector_type(8))) short short8;   // 8 bf16
typedef __attribute__((ext_vector_type(4))) float float4v;  // MFMA acc

static __device__ __forceinline__ short f2bf(float f) {
    union { float f; unsigned u; } c; c.f = f;
    unsigned r = (c.u + 0x7fffu + ((c.u >> 16) & 1u)) >> 16;  // RNE
    return (short)r;
}

// agent-scope relaxed atomic helpers (cache-bypass to coherence point; no fences)
static __device__ __forceinline__ void astore_u(unsigned* p, unsigned v) {
    __hip_atomic_store(p, v, __ATOMIC_RELAXED, __HIP_MEMORY_SCOPE_AGENT);
}
static __device__ __forceinline__ unsigned long long aload_u64(const unsigned long long* p) {
    return __hip_atomic_load(p, __ATOMIC_RELAXED, __HIP_MEMORY_SCOPE_AGENT);
}

static __device__ __forceinline__ float fsig(float v) {
    return 1.f / (1.f + __expf(-v));
}
static __device__ __forceinline__ float ftanh(float v) {
    float cl = fminf(fmaxf(v, -15.f), 15.f);   // keep __expf finite
    float e  = __expf(-2.f * cl);
    return (1.f - e) / (1.f + e);
}

// ---------------------------------------------------------------------------
// Persistent LSTM, flag-free. Grid: 256 blocks x 512 threads (8 waves).
// mc = blk & 3 (batch group; constant per XCD under blk%8 round-robin),
// jc = blk >> 2 (16-col j tile). Groups of 64 blocks share an mc chain.
//
// h exchange is SELF-VALIDATING: h word = (bf16(h) << 16) | (t & 0xffff),
// stored with one relaxed-agent 4B store. Consumers poll their own input
// words until all tags == t — the poll IS the data load. Double-buffered
// by t parity.
//
// WAR safety (no inter-block barriers): a producer writes h(t+2) into
// buf[t&1] only after its poll of h(t+1) completed, which required every
// block's h(t+1) tile, which each block published only after its own poll
// of h(t) from buf[t&1] completed — i.e. after every read of buf[t&1]@t.
//
// CRITICAL (round-2 bugfix): chunk consumption in the poll is WAVE-UNIFORM.
// Per-lane tag checks feed __all(); only when all 64 lanes hold valid data
// is the chunk consumed (a partial-exec MFMA reads unvalidated lanes'
// registers, which hold the 0xFFFF memset pattern = bf16 NaN).
// ---------------------------------------------------------------------------
__global__ __launch_bounds__(NTHR, 1) void lstm_persist(
        const float* __restrict__ x, const float* __restrict__ Wx,
        const float* __restrict__ Wh, const float* __restrict__ bias,
        float* __restrict__ out, unsigned* __restrict__ hb0,
        unsigned* __restrict__ hb1)
{
    __shared__ float part[8][16][68];   // per-wave partial gate tiles
    __shared__ float gtile[16][68];     // reduced gates
    __shared__ float sbias[64];

    const int tid  = threadIdx.x;
    const int w    = tid >> 6;
    const int lane = tid & 63;
    const int blk  = blockIdx.x;
    const int mc   = blk & 3;     // batch-row group (XCD-local under %8 RR)
    const int jc   = blk >> 2;    // 0..63  j group (16 j's)
    const int quad = lane >> 4;   // 0..3
    const int n    = lane & 15;   // MFMA row/col within tile
    const int gN   = n >> 2;      // gate index for B cols
    const int jl4  = n & 3;

    if (tid < 64) {
        int u = tid >> 4, nn = tid & 15;
        sbias[u * 16 + nn] = bias[(nn >> 2) * Hq + jc * 16 + u * 4 + (nn & 3)];
    }

    // ---- one-time: B fragments (bf16) into registers ----------------------
    // chunk s<4: Wh rows [w*128 + s*32, +32);  s>=4: Wx rows [w*128 + (s-4)*32, +32)
    short8 bs[4][8];
#pragma unroll
    for (int u = 0; u < 4; ++u) {
        const int col = gN * Hq + jc * 16 + u * 4 + jl4;
#pragma unroll
        for (int s = 0; s < 8; ++s) {
            const int kb = w * 128 + (s & 3) * 32 + quad * 8;
            const float* Wsrc = (s < 4) ? Wh : Wx;
#pragma unroll
            for (int j = 0; j < 8; ++j)
                bs[u][s][j] = f2bf(Wsrc[(size_t)(kb + j) * G4 + col]);
        }
    }

    float cstate = 0.f;          // cell state (threads 0..255)
    const int urow = tid >> 4;   // valid when tid<256
    const int ujl  = tid & 15;

    const int m_g = mc * 16 + n;                          // A row (batch)
    const float* xrow = x + (size_t)m_g * Tq * Hq + w * 128 + quad * 8;
    const size_t hoff = (size_t)m_g * Hq + w * 128 + quad * 8;   // u32 words

    float4v acc0, acc1, acc2, acc3;

    auto mfma_chunk = [&](short8 a, int s) {   // s compile-time after unroll
        acc0 = __builtin_amdgcn_mfma_f32_16x16x32_bf16(a, bs[0][s], acc0, 0, 0, 0);
        acc1 = __builtin_amdgcn_mfma_f32_16x16x32_bf16(a, bs[1][s], acc1, 0, 0, 0);
        acc2 = __builtin_amdgcn_mfma_f32_16x16x32_bf16(a, bs[2][s], acc2, 0, 0, 0);
        acc3 = __builtin_amdgcn_mfma_f32_16x16x32_bf16(a, bs[3][s], acc3, 0, 0, 0);
    };
    auto store_part = [&]() {
#pragma unroll
        for (int r = 0; r < 4; ++r) {
            part[w][quad * 4 + r][ 0 + n] = acc0[r];
            part[w][quad * 4 + r][16 + n] = acc1[r];
            part[w][quad * 4 + r][32 + n] = acc2[r];
            part[w][quad * 4 + r][48 + n] = acc3[r];
        }
    };
    auto xmfma = [&](const float4* xv) {
#pragma unroll
        for (int cs = 0; cs < 4; ++cs) {
            float4 v0 = xv[2 * cs], v1 = xv[2 * cs + 1];
            short8 a;
            a[0] = f2bf(v0.x); a[1] = f2bf(v0.y); a[2] = f2bf(v0.z); a[3] = f2bf(v0.w);
            a[4] = f2bf(v1.x); a[5] = f2bf(v1.y); a[6] = f2bf(v1.z); a[7] = f2bf(v1.w);
            mfma_chunk(a, 4 + cs);
        }
    };

    // poll-load h(t): retry per 32-k chunk until ALL LANES' 8 tags match;
    // consume each chunk (4 MFMAs, full wave) as soon as it validates.
    auto poll_h = [&](int t) {
        const unsigned* hb = (t & 1) ? hb1 : hb0;
        const unsigned long long* p = (const unsigned long long*)(hb + hoff);
        const unsigned tg = (unsigned)t;
        unsigned pend = 0xf;              // wave-uniform throughout
        unsigned long long qq[4][4];
        do {
            // issue loads for all pending chunks first (parallel RTs) ...
#pragma unroll
            for (int s = 0; s < 4; ++s)
                if (pend & (1u << s)) {
#pragma unroll
                    for (int m = 0; m < 4; ++m)
                        qq[s][m] = aload_u64(p + s * 16 + m);
                }
            // ... then validate (per-lane) / consume (wave-uniform)
#pragma unroll
            for (int s = 0; s < 4; ++s)
                if (pend & (1u << s)) {
                    bool ok = true;
#pragma unroll
                    for (int m = 0; m < 4; ++m) {
                        unsigned lo = (unsigned)qq[s][m];
                        unsigned hi = (unsigned)(qq[s][m] >> 32);
                        ok = ok && ((lo & 0xffffu) == tg) && ((hi & 0xffffu) == tg);
                    }
                    if (__all(ok)) {      // full wave valid -> safe to MFMA
                        pend &= ~(1u << s);
                        short8 a;
#pragma unroll
                        for (int m = 0; m < 4; ++m) {
                            a[2 * m]     = (short)((unsigned)qq[s][m] >> 16);
                            a[2 * m + 1] = (short)(qq[s][m] >> 48);
                        }
                        mfma_chunk(a, s);
                    }
                }
        } while (pend);
    };

    // ---- prologue: part for t=0 (x contribution only; h == 0) -------------
    {
        float4 xv[8];
#pragma unroll
        for (int cs = 0; cs < 4; ++cs) {
            const float4* q = (const float4*)(xrow + cs * 32);
            xv[2 * cs] = q[0]; xv[2 * cs + 1] = q[1];
        }
        acc0 = acc1 = acc2 = acc3 = (float4v){0, 0, 0, 0};
        xmfma(xv);
        store_part();
    }

    for (int t = 0; t < Tq; ++t) {
        __syncthreads();   // S1: part(t) complete
        // reduce 8 partials -> gates (1024 values, 2 per thread)
#pragma unroll
        for (int e = 0; e < 2; ++e) {
            int idx = tid + e * NTHR;
            int rr = idx >> 6, cc = idx & 63;
            float s = part[0][rr][cc];
#pragma unroll
            for (int ww = 1; ww < 8; ++ww) s += part[ww][rr][cc];
            gtile[rr][cc] = s + sbias[cc];
        }
        __syncthreads();   // S2: gtile ready; part free

        const bool notlast = (t + 1 < Tq);

        // issue x loads for t+1 immediately (hide under act + poll)
        float4 xv[8];
        if (notlast) {
            const float* ap = xrow + (size_t)(t + 1) * Hq;
#pragma unroll
            for (int cs = 0; cs < 4; ++cs) {
                const float4* q = (const float4*)(ap + cs * 32);
                xv[2 * cs] = q[0]; xv[2 * cs + 1] = q[1];
            }
        }

        if (tid < 256) {
            const int u = ujl >> 2, j4 = ujl & 3;
            float gi = gtile[urow][u * 16 +  0 + j4];
            float gf = gtile[urow][u * 16 +  4 + j4];
            float gg = gtile[urow][u * 16 +  8 + j4];
            float go = gtile[urow][u * 16 + 12 + j4];
            float i_ = fsig(gi);
            float f_ = fsig(gf);
            float g_ = ftanh(gg);
            float o_ = fsig(go);
            cstate = f_ * cstate + i_ * g_;
            float hn = o_ * ftanh(cstate);
            const int bg = mc * 16 + urow, jg = jc * 16 + ujl;
            if (notlast) {
                unsigned* hw = (t & 1) ? hb1 : hb0;
                astore_u(hw + (size_t)bg * Hq + jg,
                         ((unsigned)(unsigned short)f2bf(hn) << 16) | (unsigned)t);
            }
            out[((size_t)bg * Tq + t) * Hq + jg] = hn;
        }
        // a thread polls words it itself stores — forbid the compiler from
        // sinking the publish below the poll loop
        asm volatile("" ::: "memory");

        if (notlast) {
            acc0 = acc1 = acc2 = acc3 = (float4v){0, 0, 0, 0};
            poll_h(t);     // h(t) chunks -> MFMA as they arrive
            xmfma(xv);     // x(t+1) chunks
            store_part();  // part for t+1
        }
    }
}

extern "C" void kernel_launch(void* const* d_in, const int* in_sizes, int n_in,
                              void* d_out, int out_size, void* d_ws, size_t ws_size,
                              hipStream_t stream) {
    const float* x    = (const float*)d_in[0];
    const float* Wx   = (const float*)d_in[1];
    const float* Wh   = (const float*)d_in[2];
    const float* bias = (const float*)d_in[3];
    float* out = (float*)d_out;

    // ws layout: hb0[64*1024] u32 (256 KB) | hb1[64*1024] u32 (256 KB)
    unsigned* hb0 = (unsigned*)d_ws;
    unsigned* hb1 = hb0 + Bq * Hq;

    // invalidate all tags (0xFFFF != any t < 512); also clears stale tags
    // from previous launches of the same buffer
    hipMemsetAsync(d_ws, 0xFF, (size_t)2 * Bq * Hq * 4, stream);

    void* args[] = {(void*)&x, (void*)&Wx, (void*)&Wh, (void*)&bias,
                    (void*)&out, (void*)&hb0, (void*)&hb1};
    hipLaunchCooperativeKernel((const void*)lstm_persist, dim3(NBLK), dim3(NTHR),
                               args, 0, stream);
}

// Round 4
// 3770.450 us; speedup vs baseline: 1.2290x; 1.2290x over previous
//
#include <hip/hip_runtime.h>
#include <math.h>

#define Bq 64
#define Tq 512
#define Hq 1024
#define G4 4096
#define NBLK 256
#define NTHR 512

typedef __attribute__((ext_vector_type(8))) short short8;    // 8 bf16
typedef __attribute__((ext_vector_type(4))) float float4v;   // MFMA acc
typedef __attribute__((ext_vector_type(4))) unsigned uint4v; // dwordx4 payload

static __device__ __forceinline__ short f2bf(float f) {
    union { float f; unsigned u; } c; c.f = f;
    unsigned r = (c.u + 0x7fffu + ((c.u >> 16) & 1u)) >> 16;  // RNE
    return (short)r;
}

// single-word publish (agent-scope relaxed, cache-bypass; fire-and-forget)
static __device__ __forceinline__ void astore_u(unsigned* p, unsigned v) {
    __hip_atomic_store(p, v, __ATOMIC_RELAXED, __HIP_MEMORY_SCOPE_AGENT);
}

static __device__ __forceinline__ float fsig(float v) {
    return 1.f / (1.f + __expf(-v));
}
static __device__ __forceinline__ float ftanh(float v) {
    float cl = fminf(fmaxf(v, -15.f), 15.f);   // keep __expf finite
    float e  = __expf(-2.f * cl);
    return (1.f - e) / (1.f + e);
}

// ---------------------------------------------------------------------------
// Persistent LSTM, flag-free. Grid: 256 blocks x 512 threads (8 waves).
// mc = blk & 3 (constant per XCD under blk%8 round-robin), jc = blk >> 2.
//
// h exchange is SELF-VALIDATING: h word = (bf16(h) << 16) | (t & 0xffff).
// Consumers poll their own input words until all tags == t; the poll IS the
// data load. Double-buffered by t parity. WAR-safe by the dependency chain
// (producer writes h(t+2) into buf[t&1] only after consuming h(t+1), which
// required every block to have finished reading buf[t&1]@t).
//
// ROUND-4 KEY FIX: rounds 0-3 were dominated by SERIALIZED agent-scope
// atomic loads (step time tracked the atomic-load count, ~1 LLC round-trip
// each). The h-poll now issues all 8 global_load_dwordx4 (sc0 sc1 =
// coherent cache-bypass) back-to-back in ONE inline-asm block with a single
// s_waitcnt vmcnt(0): one poll iteration = one LLC round-trip (~0.4us)
// for the full 128B/lane instead of 16 serialized round-trips (~6us).
//
// Poll consumption stays WAVE-UNIFORM (__all over all 32 tags) — a
// partial-exec MFMA would read unvalidated lanes' registers (0xFFFF
// memset pattern = bf16 NaN).
// ---------------------------------------------------------------------------
__global__ __launch_bounds__(NTHR, 1) void lstm_persist(
        const float* __restrict__ x, const float* __restrict__ Wx,
        const float* __restrict__ Wh, const float* __restrict__ bias,
        float* __restrict__ out, unsigned* __restrict__ hb0,
        unsigned* __restrict__ hb1)
{
    __shared__ float part[8][16][68];   // per-wave partial gate tiles
    __shared__ float gtile[16][68];     // reduced gates
    __shared__ float sbias[64];

    const int tid  = threadIdx.x;
    const int w    = tid >> 6;
    const int lane = tid & 63;
    const int blk  = blockIdx.x;
    const int mc   = blk & 3;     // batch-row group (XCD-local under %8 RR)
    const int jc   = blk >> 2;    // 0..63  j group (16 j's)
    const int quad = lane >> 4;   // 0..3
    const int n    = lane & 15;   // MFMA row/col within tile
    const int gN   = n >> 2;      // gate index for B cols
    const int jl4  = n & 3;

    if (tid < 64) {
        int u = tid >> 4, nn = tid & 15;
        sbias[u * 16 + nn] = bias[(nn >> 2) * Hq + jc * 16 + u * 4 + (nn & 3)];
    }

    // ---- one-time: B fragments (bf16) into registers ----------------------
    // chunk s<4: Wh rows [w*128 + s*32, +32);  s>=4: Wx rows [w*128 + (s-4)*32, +32)
    short8 bs[4][8];
#pragma unroll
    for (int u = 0; u < 4; ++u) {
        const int col = gN * Hq + jc * 16 + u * 4 + jl4;
#pragma unroll
        for (int s = 0; s < 8; ++s) {
            const int kb = w * 128 + (s & 3) * 32 + quad * 8;
            const float* Wsrc = (s < 4) ? Wh : Wx;
#pragma unroll
            for (int j = 0; j < 8; ++j)
                bs[u][s][j] = f2bf(Wsrc[(size_t)(kb + j) * G4 + col]);
        }
    }

    float cstate = 0.f;          // cell state (threads 0..255)
    const int urow = tid >> 4;   // valid when tid<256
    const int ujl  = tid & 15;

    const int m_g = mc * 16 + n;                          // A row (batch)
    const float* xrow = x + (size_t)m_g * Tq * Hq + w * 128 + quad * 8;
    const size_t hoff = (size_t)m_g * Hq + w * 128 + quad * 8;   // u32 words

    float4v acc0, acc1, acc2, acc3;

    auto mfma_chunk = [&](short8 a, int s) {   // s compile-time after unroll
        acc0 = __builtin_amdgcn_mfma_f32_16x16x32_bf16(a, bs[0][s], acc0, 0, 0, 0);
        acc1 = __builtin_amdgcn_mfma_f32_16x16x32_bf16(a, bs[1][s], acc1, 0, 0, 0);
        acc2 = __builtin_amdgcn_mfma_f32_16x16x32_bf16(a, bs[2][s], acc2, 0, 0, 0);
        acc3 = __builtin_amdgcn_mfma_f32_16x16x32_bf16(a, bs[3][s], acc3, 0, 0, 0);
    };
    auto store_part = [&]() {
#pragma unroll
        for (int r = 0; r < 4; ++r) {
            part[w][quad * 4 + r][ 0 + n] = acc0[r];
            part[w][quad * 4 + r][16 + n] = acc1[r];
            part[w][quad * 4 + r][32 + n] = acc2[r];
            part[w][quad * 4 + r][48 + n] = acc3[r];
        }
    };
    auto xmfma = [&](const float4* xv) {
#pragma unroll
        for (int cs = 0; cs < 4; ++cs) {
            float4 v0 = xv[2 * cs], v1 = xv[2 * cs + 1];
            short8 a;
            a[0] = f2bf(v0.x); a[1] = f2bf(v0.y); a[2] = f2bf(v0.z); a[3] = f2bf(v0.w);
            a[4] = f2bf(v1.x); a[5] = f2bf(v1.y); a[6] = f2bf(v1.z); a[7] = f2bf(v1.w);
            mfma_chunk(a, 4 + cs);
        }
    };

    // poll-load h(t): ONE batched round-trip per iteration.
    // Per-lane layout: 4 chunks of 8 u32 words at byte offsets s*128 (+0,+16).
    auto poll_h = [&](int t) {
        const unsigned* hb = (t & 1) ? hb1 : hb0;
        const unsigned* base = hb + hoff;
        const unsigned tg = (unsigned)t;
        uint4v q0, q1, q2, q3, q4, q5, q6, q7;
        for (;;) {
            asm volatile(
                "global_load_dwordx4 %[a0], %[ad], off sc0 sc1\n\t"
                "global_load_dwordx4 %[a1], %[ad], off offset:16 sc0 sc1\n\t"
                "global_load_dwordx4 %[a2], %[ad], off offset:128 sc0 sc1\n\t"
                "global_load_dwordx4 %[a3], %[ad], off offset:144 sc0 sc1\n\t"
                "global_load_dwordx4 %[a4], %[ad], off offset:256 sc0 sc1\n\t"
                "global_load_dwordx4 %[a5], %[ad], off offset:272 sc0 sc1\n\t"
                "global_load_dwordx4 %[a6], %[ad], off offset:384 sc0 sc1\n\t"
                "global_load_dwordx4 %[a7], %[ad], off offset:400 sc0 sc1\n\t"
                "s_waitcnt vmcnt(0)"
                : [a0]"=v"(q0), [a1]"=v"(q1), [a2]"=v"(q2), [a3]"=v"(q3),
                  [a4]"=v"(q4), [a5]"=v"(q5), [a6]"=v"(q6), [a7]"=v"(q7)
                : [ad]"v"(base)
                : "memory");
            // validate all 32 tags (per-lane), consume wave-uniformly
            unsigned bad = 0;
#pragma unroll
            for (int m = 0; m < 4; ++m) {
                bad |= (q0[m] ^ tg) & 0xffffu; bad |= (q1[m] ^ tg) & 0xffffu;
                bad |= (q2[m] ^ tg) & 0xffffu; bad |= (q3[m] ^ tg) & 0xffffu;
                bad |= (q4[m] ^ tg) & 0xffffu; bad |= (q5[m] ^ tg) & 0xffffu;
                bad |= (q6[m] ^ tg) & 0xffffu; bad |= (q7[m] ^ tg) & 0xffffu;
            }
            if (__all(bad == 0)) break;   // full wave valid -> safe to MFMA
        }
        auto mk = [&](uint4v qa, uint4v qb) {
            short8 a;
            a[0] = (short)(qa[0] >> 16); a[1] = (short)(qa[1] >> 16);
            a[2] = (short)(qa[2] >> 16); a[3] = (short)(qa[3] >> 16);
            a[4] = (short)(qb[0] >> 16); a[5] = (short)(qb[1] >> 16);
            a[6] = (short)(qb[2] >> 16); a[7] = (short)(qb[3] >> 16);
            return a;
        };
        mfma_chunk(mk(q0, q1), 0);
        mfma_chunk(mk(q2, q3), 1);
        mfma_chunk(mk(q4, q5), 2);
        mfma_chunk(mk(q6, q7), 3);
    };

    // ---- prologue: part for t=0 (x contribution only; h == 0) -------------
    {
        float4 xv[8];
#pragma unroll
        for (int cs = 0; cs < 4; ++cs) {
            const float4* q = (const float4*)(xrow + cs * 32);
            xv[2 * cs] = q[0]; xv[2 * cs + 1] = q[1];
        }
        acc0 = acc1 = acc2 = acc3 = (float4v){0, 0, 0, 0};
        xmfma(xv);
        store_part();
    }

    for (int t = 0; t < Tq; ++t) {
        __syncthreads();   // S1: part(t) complete
        // reduce 8 partials -> gates (1024 values, 2 per thread)
#pragma unroll
        for (int e = 0; e < 2; ++e) {
            int idx = tid + e * NTHR;
            int rr = idx >> 6, cc = idx & 63;
            float s = part[0][rr][cc];
#pragma unroll
            for (int ww = 1; ww < 8; ++ww) s += part[ww][rr][cc];
            gtile[rr][cc] = s + sbias[cc];
        }
        __syncthreads();   // S2: gtile ready; part free

        const bool notlast = (t + 1 < Tq);

        // issue x loads for t+1 immediately (in flight under act phase)
        float4 xv[8];
        if (notlast) {
            const float* ap = xrow + (size_t)(t + 1) * Hq;
#pragma unroll
            for (int cs = 0; cs < 4; ++cs) {
                const float4* q = (const float4*)(ap + cs * 32);
                xv[2 * cs] = q[0]; xv[2 * cs + 1] = q[1];
            }
        }

        if (tid < 256) {
            const int u = ujl >> 2, j4 = ujl & 3;
            float gi = gtile[urow][u * 16 +  0 + j4];
            float gf = gtile[urow][u * 16 +  4 + j4];
            float gg = gtile[urow][u * 16 +  8 + j4];
            float go = gtile[urow][u * 16 + 12 + j4];
            float i_ = fsig(gi);
            float f_ = fsig(gf);
            float g_ = ftanh(gg);
            float o_ = fsig(go);
            cstate = f_ * cstate + i_ * g_;
            float hn = o_ * ftanh(cstate);
            const int bg = mc * 16 + urow, jg = jc * 16 + ujl;
            if (notlast) {
                unsigned* hw = (t & 1) ? hb1 : hb0;
                astore_u(hw + (size_t)bg * Hq + jg,
                         ((unsigned)(unsigned short)f2bf(hn) << 16) | (unsigned)t);
            }
            out[((size_t)bg * Tq + t) * Hq + jg] = hn;
        }
        // a thread polls words it itself stores — forbid the compiler from
        // sinking the publish below the poll loop
        asm volatile("" ::: "memory");

        if (notlast) {
            acc0 = acc1 = acc2 = acc3 = (float4v){0, 0, 0, 0};
            xmfma(xv);     // x(t+1) first: fills the publish-latency window,
                           // frees xv regs before the poll payload goes live
            poll_h(t);     // h(t): one batched LLC round-trip per iteration
            store_part();  // part for t+1
        }
    }
}

extern "C" void kernel_launch(void* const* d_in, const int* in_sizes, int n_in,
                              void* d_out, int out_size, void* d_ws, size_t ws_size,
                              hipStream_t stream) {
    const float* x    = (const float*)d_in[0];
    const float* Wx   = (const float*)d_in[1];
    const float* Wh   = (const float*)d_in[2];
    const float* bias = (const float*)d_in[3];
    float* out = (float*)d_out;

    // ws layout: hb0[64*1024] u32 (256 KB) | hb1[64*1024] u32 (256 KB)
    unsigned* hb0 = (unsigned*)d_ws;
    unsigned* hb1 = hb0 + Bq * Hq;

    // invalidate all tags (0xFFFF != any t < 512)
    hipMemsetAsync(d_ws, 0xFF, (size_t)2 * Bq * Hq * 4, stream);

    void* args[] = {(void*)&x, (void*)&Wx, (void*)&Wh, (void*)&bias,
                    (void*)&out, (void*)&hb0, (void*)&hb1};
    hipLaunchCooperativeKernel((const void*)lstm_persist, dim3(NBLK), dim3(NTHR),
                               args, 0, stream);
}